// Round 5
// baseline (6525.999 us; speedup 1.0000x reference)
//
#include <hip/hip_runtime.h>

// PointerNetwork: B=64, N=512, E=512, 2E=1024, T=64 decode steps.
// Round 4 (resubmit after GPU-acquisition timeout): ONE kernel per decode step
// (64 dependent launches instead of 192). Intra-kernel producer->consumer
// flags (agent-scope release/acquire) order gates->hx (blocks 0..255) -> q
// (same blocks) -> scores (all 1024 blocks). All 1024 blocks are co-resident
// (launch_bounds(256,4) => >=4 blocks/CU), so spin-waits cannot deadlock.
// All f32 (argmax chain is precision-critical). Indices written as float.

#define DEV __device__ __forceinline__

DEV float sigm(float x) { return __fdividef(1.0f, 1.0f + __expf(-x)); }
DEV float tanh_fast(float x) {
  float e = __expf(2.0f * x);                 // tanh = 1 - 2/(e^2x+1)
  return 1.0f - __fdividef(2.0f, e + 1.0f);   // inf-safe at both ends
}

// monotone f32 -> u32 key (order-preserving), packed with (511-n) so that
// u64 atomicMax = (max score, ties -> smallest n)  == jnp.argmax semantics.
DEV unsigned long long pack_score(float s, int n) {
  unsigned u = __float_as_uint(s);
  unsigned key = (u & 0x80000000u) ? ~u : (u | 0x80000000u);
  return ((unsigned long long)key << 32) | (unsigned)(511 - n);
}
DEV float unpack_score(unsigned long long p) {
  unsigned key = (unsigned)(p >> 32);
  unsigned u = (key & 0x80000000u) ? (key & 0x7fffffffu) : ~key;
  return __uint_as_float(u);
}
DEV int unpack_idx(unsigned long long p) { return 511 - (int)(p & 0xffffu); }

#define FMA4(acc, xv, wv)                                                      \
  acc = fmaf((xv).x, (wv).x, acc); acc = fmaf((xv).y, (wv).y, acc);            \
  acc = fmaf((xv).z, (wv).z, acc); acc = fmaf((xv).w, (wv).w, acc)

// ---------------- enc GEMM: C[32768x512] = A[32768x1024] @ B[512x1024]^T + bias
__global__ __launch_bounds__(256) void kenc(const float* __restrict__ A,
                                            const float* __restrict__ Bm,
                                            const float* __restrict__ bias,
                                            float* __restrict__ C) {
  __shared__ float a_s[16][132];
  __shared__ float b_s[16][132];
  const int t = threadIdx.x;
  const int row = t >> 1;            // 0..127
  const int kq = (t & 1) * 8;        // 0 or 8
  const float* Arow = A + (blockIdx.x * 128 + row) * 1024 + kq;
  const float* Brow = Bm + (blockIdx.y * 128 + row) * 1024 + kq;
  const int tx = t & 15, ty = t >> 4;
  float acc[8][8] = {};
  for (int k0 = 0; k0 < 1024; k0 += 16) {
    float4 av0 = *(const float4*)(Arow + k0);
    float4 av1 = *(const float4*)(Arow + k0 + 4);
    float4 bv0 = *(const float4*)(Brow + k0);
    float4 bv1 = *(const float4*)(Brow + k0 + 4);
    __syncthreads();
    a_s[kq+0][row]=av0.x; a_s[kq+1][row]=av0.y; a_s[kq+2][row]=av0.z; a_s[kq+3][row]=av0.w;
    a_s[kq+4][row]=av1.x; a_s[kq+5][row]=av1.y; a_s[kq+6][row]=av1.z; a_s[kq+7][row]=av1.w;
    b_s[kq+0][row]=bv0.x; b_s[kq+1][row]=bv0.y; b_s[kq+2][row]=bv0.z; b_s[kq+3][row]=bv0.w;
    b_s[kq+4][row]=bv1.x; b_s[kq+5][row]=bv1.y; b_s[kq+6][row]=bv1.z; b_s[kq+7][row]=bv1.w;
    __syncthreads();
    #pragma unroll
    for (int k = 0; k < 16; ++k) {
      float a[8], b[8];
      *(float4*)(a)   = *(const float4*)&a_s[k][ty*4];
      *(float4*)(a+4) = *(const float4*)&a_s[k][64 + ty*4];
      *(float4*)(b)   = *(const float4*)&b_s[k][tx*4];
      *(float4*)(b+4) = *(const float4*)&b_s[k][64 + tx*4];
      #pragma unroll
      for (int i = 0; i < 8; ++i)
        #pragma unroll
        for (int j = 0; j < 8; ++j)
          acc[i][j] = fmaf(a[i], b[j], acc[i][j]);
    }
  }
  const int mb = blockIdx.x * 128;
  const int eb = blockIdx.y * 128;
  float4 bv0 = *(const float4*)&bias[eb + tx*4];
  float4 bv1 = *(const float4*)&bias[eb + 64 + tx*4];
  #pragma unroll
  for (int i = 0; i < 8; ++i) {
    const int r = mb + ((i < 4) ? (ty*4 + i) : (64 + ty*4 + (i - 4)));
    float* orow = C + r * 512 + eb;
    float4 o0, o1;
    o0.x=acc[i][0]+bv0.x; o0.y=acc[i][1]+bv0.y; o0.z=acc[i][2]+bv0.z; o0.w=acc[i][3]+bv0.w;
    o1.x=acc[i][4]+bv1.x; o1.y=acc[i][5]+bv1.y; o1.z=acc[i][6]+bv1.z; o1.w=acc[i][7]+bv1.w;
    *(float4*)(orow + tx*4) = o0;
    *(float4*)(orow + 64 + tx*4) = o1;
  }
}

// flag helpers (agent scope; same mechanism as the round-2/3 atomics that
// were verified correct across XCDs)
DEV void flag_signal(unsigned* p) {
  __hip_atomic_fetch_add(p, 1u, __ATOMIC_RELEASE, __HIP_MEMORY_SCOPE_AGENT);
}
DEV void flag_wait(unsigned* p, unsigned target) {
  while (__hip_atomic_load(p, __ATOMIC_RELAXED, __HIP_MEMORY_SCOPE_AGENT) < target)
    __builtin_amdgcn_s_sleep(8);
  __builtin_amdgcn_fence(__ATOMIC_ACQUIRE, "agent");
}

// ---------------- fused per-step kernel. 1024 blocks x 256 threads.
// blocks 0..255: [logp/idx of t-1] + gather + gates->hx  |flag|  q  |flag|
// all blocks:    scores chunk (b=g>>4, 32 n) + packed atomicMax -> mall[t]
__global__ __launch_bounds__(256, 4) void kdec(
    const float* __restrict__ TE, const float* __restrict__ encd,
    const float* __restrict__ W_ih, const float* __restrict__ b_ih,
    const float* __restrict__ b_hh, const float* __restrict__ Wd,
    const float* __restrict__ bd, const float* __restrict__ wr,
    const float* __restrict__ br, const float* __restrict__ enc,
    float* __restrict__ scores, float* __restrict__ hx, float* __restrict__ q,
    unsigned long long* __restrict__ mall, unsigned* __restrict__ flags,
    float* __restrict__ out_logp, float* __restrict__ out_idx, int step) {
  __shared__ int   idx_s[64];
  __shared__ float mx_s[64];
  __shared__ float wsum_s[4];
  __shared__ float part_s[4][64][6];
  __shared__ float partq_s[4][64][2];
  __shared__ unsigned long long lmax;
  const int g = blockIdx.x;
  const int t = threadIdx.x;
  const int lane = t & 63;
  const int wu = __builtin_amdgcn_readfirstlane(t >> 6);
  unsigned* hx_done = flags + step * 2;
  unsigned* q_done  = hx_done + 1;
  const unsigned long long* mprev = mall + (step - 1) * 64;  // valid iff step>0
  unsigned long long* mcur = mall + step * 64;
  if (t == 0) lmax = 0ULL;

  if (g < 256) {
    // ---- A1: previous step's argmax/max from packed atomics
    if (step > 0 && t < 64) {
      unsigned long long p = mprev[t];
      idx_s[t] = unpack_idx(p);
      mx_s[t]  = unpack_score(p);
    }
    __syncthreads();

    // ---- A2: blocks 0..63 write logp row + idx for step-1
    if (step > 0 && g < 64) {
      const float* srow = scores + g * 512;
      const float mx = mx_s[g];
      float ssum = __expf(srow[t] - mx) + __expf(srow[t + 256] - mx);
      #pragma unroll
      for (int m = 1; m <= 32; m <<= 1) ssum += __shfl_xor(ssum, m);
      if (lane == 0) wsum_s[wu] = ssum;
    }
    __syncthreads();
    if (step > 0 && g < 64) {
      const float* srow = scores + g * 512;
      const float lse = mx_s[g] + __logf(wsum_s[0] + wsum_s[1] + wsum_s[2] + wsum_s[3]);
      float* orow = out_logp + (g * 64 + (step - 1)) * 512;
      orow[t]       = srow[t]       - lse;
      orow[t + 256] = srow[t + 256] - lse;
      if (t == 0) out_idx[g * 64 + (step - 1)] = (float)idx_s[g];
    }

    // ---- A3: gates GEMM slice -> hx cols 2g, 2g+1 (i,g,o gates; f dead)
    {
      const int k0 = 2 * g, k1 = 2 * g + 1;
      const int dbase = wu * 256;
      const float* p0 = W_ih + (k0        ) * 1024 + dbase;
      const float* p1 = W_ih + (k1        ) * 1024 + dbase;
      const float* p2 = W_ih + (1024 + k0) * 1024 + dbase;
      const float* p3 = W_ih + (1024 + k1) * 1024 + dbase;
      const float* p4 = W_ih + (1536 + k0) * 1024 + dbase;
      const float* p5 = W_ih + (1536 + k1) * 1024 + dbase;
      const float* xr = (step == 0) ? (encd + lane * 1024 + dbase)
                                    : (TE + (lane * 512 + idx_s[lane]) * 1024 + dbase);
      float a0=0, a1=0, a2=0, a3=0, a4=0, a5=0;
      #pragma unroll 4
      for (int d = 0; d < 256; d += 4) {
        float4 xv = *(const float4*)(xr + d);
        float4 v0 = *(const float4*)(p0 + d);
        float4 v1 = *(const float4*)(p1 + d);
        float4 v2 = *(const float4*)(p2 + d);
        float4 v3 = *(const float4*)(p3 + d);
        float4 v4 = *(const float4*)(p4 + d);
        float4 v5 = *(const float4*)(p5 + d);
        FMA4(a0, xv, v0); FMA4(a1, xv, v1); FMA4(a2, xv, v2);
        FMA4(a3, xv, v3); FMA4(a4, xv, v4); FMA4(a5, xv, v5);
      }
      part_s[wu][lane][0]=a0; part_s[wu][lane][1]=a1; part_s[wu][lane][2]=a2;
      part_s[wu][lane][3]=a3; part_s[wu][lane][4]=a4; part_s[wu][lane][5]=a5;
      __syncthreads();
      if (t < 64) {
        float s0=0, s1=0, s2=0, s3=0, s4=0, s5=0;
        #pragma unroll
        for (int u = 0; u < 4; ++u) {
          s0 += part_s[u][t][0]; s1 += part_s[u][t][1]; s2 += part_s[u][t][2];
          s3 += part_s[u][t][3]; s4 += part_s[u][t][4]; s5 += part_s[u][t][5];
        }
        const float gi0 = s0 + b_ih[k0] + b_hh[k0];
        const float gi1 = s1 + b_ih[k1] + b_hh[k1];
        const float gg0 = s2 + b_ih[1024 + k0] + b_hh[1024 + k0];
        const float gg1 = s3 + b_ih[1024 + k1] + b_hh[1024 + k1];
        const float go0 = s4 + b_ih[1536 + k0] + b_hh[1536 + k0];
        const float go1 = s5 + b_ih[1536 + k1] + b_hh[1536 + k1];
        const float c0 = sigm(gi0) * tanh_fast(gg0);
        const float c1 = sigm(gi1) * tanh_fast(gg1);
        hx[t * 512 + k0] = sigm(go0) * tanh_fast(c0);
        hx[t * 512 + k1] = sigm(go1) * tanh_fast(c1);
      }
    }
    __syncthreads();                       // hx stores drained (vmcnt0 at barrier)
    if (t == 0) {
      flag_signal(hx_done);
      flag_wait(hx_done, 256u);            // all hx slices visible
    }
    __syncthreads();

    // ---- Q: q cols 2g, 2g+1
    {
      const int dbase = wu * 128;
      const int e0 = g * 2;
      const float* w0 = Wd + (e0 + 0) * 512 + dbase;
      const float* w1 = Wd + (e0 + 1) * 512 + dbase;
      const float* xr = hx + lane * 512 + dbase;
      float a0=0, a1=0;
      #pragma unroll 8
      for (int d = 0; d < 128; d += 4) {
        float4 xv = *(const float4*)(xr + d);
        float4 v0 = *(const float4*)(w0 + d);
        float4 v1 = *(const float4*)(w1 + d);
        FMA4(a0, xv, v0); FMA4(a1, xv, v1);
      }
      partq_s[wu][lane][0]=a0; partq_s[wu][lane][1]=a1;
      __syncthreads();
      if (t < 64) {
        float2 r;
        r.x = partq_s[0][t][0]+partq_s[1][t][0]+partq_s[2][t][0]+partq_s[3][t][0] + bd[e0+0];
        r.y = partq_s[0][t][1]+partq_s[1][t][1]+partq_s[2][t][1]+partq_s[3][t][1] + bd[e0+1];
        *(float2*)(q + t * 512 + e0) = r;
      }
    }
    __syncthreads();                       // q stores drained
    if (t == 0) flag_signal(q_done);
  }

  // ---- S: all 1024 blocks wait for q, then scores chunk
  if (t == 0) flag_wait(q_done, 256u);
  __syncthreads();
  {
    const int b = g >> 4, c = g & 15;
    const int le = lane & 15, nl = lane >> 4;
    const float C2 = 2.8853900817779268f;   // 2*log2(e)
    float4 wv[8], cq[8];
    const float* qrow = q + b * 512 + le * 4;
    const float* wrp  = wr + le * 4;
    float swv = 0.0f;
    #pragma unroll
    for (int j = 0; j < 8; ++j) {
      wv[j] = *(const float4*)(wrp + 64 * j);
      swv += wv[j].x + wv[j].y + wv[j].z + wv[j].w;
      float4 qv = *(const float4*)(qrow + 64 * j);
      cq[j].x = C2*qv.x; cq[j].y = C2*qv.y; cq[j].z = C2*qv.z; cq[j].w = C2*qv.w;
    }
    swv += __shfl_xor(swv, 1); swv += __shfl_xor(swv, 2);
    swv += __shfl_xor(swv, 4); swv += __shfl_xor(swv, 8);
    const float brv = br[0];
    #pragma unroll
    for (int i = 0; i < 2; ++i) {
      const int n = c * 32 + wu * 8 + i * 4 + nl;
      const float* erow = enc + (b * 512 + n) * 512 + le * 4;
      float acc = 0.0f;
      #pragma unroll
      for (int j = 0; j < 8; ++j) {
        float4 ev = *(const float4*)(erow + 64 * j);
        acc = fmaf(wv[j].x, __fdividef(1.0f, __builtin_exp2f(fmaf(C2, ev.x, cq[j].x)) + 1.0f), acc);
        acc = fmaf(wv[j].y, __fdividef(1.0f, __builtin_exp2f(fmaf(C2, ev.y, cq[j].y)) + 1.0f), acc);
        acc = fmaf(wv[j].z, __fdividef(1.0f, __builtin_exp2f(fmaf(C2, ev.z, cq[j].z)) + 1.0f), acc);
        acc = fmaf(wv[j].w, __fdividef(1.0f, __builtin_exp2f(fmaf(C2, ev.w, cq[j].w)) + 1.0f), acc);
      }
      acc += __shfl_xor(acc, 1); acc += __shfl_xor(acc, 2);
      acc += __shfl_xor(acc, 4); acc += __shfl_xor(acc, 8);
      if (le == 0) {
        const float sc = swv - 2.0f * acc + brv;
        scores[b * 512 + n] = sc;
        atomicMax(&lmax, pack_score(sc, n));
      }
    }
  }
  __syncthreads();
  if (t == 0) atomicMax(&mcur[g >> 4], lmax);
}

// ---------------- final-step softmax/argmax (writes t=63 outputs)
__global__ __launch_bounds__(256) void kfin(const float* __restrict__ scores,
                                            const unsigned long long* __restrict__ mtop,
                                            float* __restrict__ out_logp,
                                            float* __restrict__ out_idx) {
  __shared__ float sw[4];
  const int b = blockIdx.x, t = threadIdx.x, lane = t & 63, w = t >> 6;
  const float* srow = scores + b * 512;
  const float s1 = srow[t], s2 = srow[t + 256];
  const unsigned long long p = mtop[b];
  const float mx = unpack_score(p);
  float ssum = __expf(s1 - mx) + __expf(s2 - mx);
  #pragma unroll
  for (int m = 1; m <= 32; m <<= 1) ssum += __shfl_xor(ssum, m);
  if (lane == 0) sw[w] = ssum;
  __syncthreads();
  const float lse = mx + __logf(sw[0] + sw[1] + sw[2] + sw[3]);
  float* orow = out_logp + (b * 64 + 63) * 512;
  orow[t]       = s1 - lse;
  orow[t + 256] = s2 - lse;
  if (t == 0) out_idx[b * 64 + 63] = (float)unpack_idx(p);
}

extern "C" void kernel_launch(void* const* d_in, const int* in_sizes, int n_in,
                              void* d_out, int out_size, void* d_ws, size_t ws_size,
                              hipStream_t stream) {
  const float* TE   = (const float*)d_in[0];   // [64,512,1024]
  const float* encd = (const float*)d_in[1];   // [64,1024]
  const float* W_ih = (const float*)d_in[2];   // [2048,1024]
  const float* b_ih = (const float*)d_in[3];   // [2048]
  const float* b_hh = (const float*)d_in[4];   // [2048]
  const float* Wd   = (const float*)d_in[5];   // [512,512]
  const float* bd   = (const float*)d_in[6];   // [512]
  const float* We   = (const float*)d_in[7];   // [512,1024]
  const float* be   = (const float*)d_in[8];   // [512]
  const float* wr   = (const float*)d_in[9];   // [512]
  const float* br   = (const float*)d_in[10];  // [1]

  float* out     = (float*)d_out;              // logp [64][64][512]
  float* out_idx = out + 64 * 64 * 512;        // indices as float [64][64]

  float* enc    = (float*)d_ws;                // 16,777,216 f (64 MB)
  float* scores = enc + 16777216;              // 32,768 f
  float* hx     = scores + 32768;              // 32,768 f
  float* q      = hx + 32768;                  // 32,768 f
  unsigned long long* mall = (unsigned long long*)(q + 32768);  // [64][64] u64
  unsigned* flags = (unsigned*)(mall + 64 * 64);                // [64][2] u32

  hipMemsetAsync(mall, 0, 64 * 64 * 8 + 64 * 2 * 4, stream);
  kenc<<<dim3(256, 4), 256, 0, stream>>>(TE, We, be, enc);
  for (int t = 0; t < 64; ++t) {
    kdec<<<1024, 256, 0, stream>>>(TE, encd, W_ih, b_ih, b_hh, Wd, bd, wr, br,
                                   enc, scores, hx, q, mall, flags, out,
                                   out_idx, t);
  }
  kfin<<<64, 256, 0, stream>>>(scores, mall + 63 * 64, out, out_idx);
}

// Round 6
// 5266.430 us; speedup vs baseline: 1.2392x; 1.2392x over previous
//
#include <hip/hip_runtime.h>

// PointerNetwork: B=64, N=512, E=512, 2E=1024, T=64 decode steps.
// Round 6: one kernel per step (64 launches), FENCE-FREE cross-block dataflow.
// Rounds 2/5 showed agent-scope acquire/release fences flush per-XCD L2
// (~1280 fences/step = 2x regression). Here hx and q cross blocks as RELAXED
// agent-scope atomic u64 ops (per-instruction cache bypass, no invalidates);
// flags are relaxed counters; ordering = __syncthreads (vmcnt0) before signal.
// logp of step t-1 runs on idle blocks 960..1023 (inputs cross the kernel
// boundary) concurrently with the gates phase.
// All f32 (argmax chain is precision-critical). Indices written as float.

#define DEV __device__ __forceinline__

DEV float sigm(float x) { return __fdividef(1.0f, 1.0f + __expf(-x)); }
DEV float tanh_fast(float x) {
  float e = __expf(2.0f * x);                 // tanh = 1 - 2/(e^2x+1)
  return 1.0f - __fdividef(2.0f, e + 1.0f);   // inf-safe at both ends
}

// monotone f32 -> u32 key (order-preserving), packed with (511-n) so that
// u64 atomicMax = (max score, ties -> smallest n)  == jnp.argmax semantics.
DEV unsigned long long pack_score(float s, int n) {
  unsigned u = __float_as_uint(s);
  unsigned key = (u & 0x80000000u) ? ~u : (u | 0x80000000u);
  return ((unsigned long long)key << 32) | (unsigned)(511 - n);
}
DEV float unpack_score(unsigned long long p) {
  unsigned key = (unsigned)(p >> 32);
  unsigned u = (key & 0x80000000u) ? (key & 0x7fffffffu) : ~key;
  return __uint_as_float(u);
}
DEV int unpack_idx(unsigned long long p) { return 511 - (int)(p & 0xffffu); }

// relaxed agent-scope (coherent-point) u64 data movement — NO fences
union F2U { float2 f; unsigned long long u; };
DEV void st_f2(unsigned long long* p, float a, float b) {
  F2U v; v.f.x = a; v.f.y = b;
  __hip_atomic_store(p, v.u, __ATOMIC_RELAXED, __HIP_MEMORY_SCOPE_AGENT);
}
DEV float2 ld_f2(const unsigned long long* p) {
  F2U v;
  v.u = __hip_atomic_load(p, __ATOMIC_RELAXED, __HIP_MEMORY_SCOPE_AGENT);
  return v.f;
}
DEV void sig(unsigned* p) {
  __hip_atomic_fetch_add(p, 1u, __ATOMIC_RELAXED, __HIP_MEMORY_SCOPE_AGENT);
}
DEV void waitge(unsigned* p, unsigned tgt) {
  while (__hip_atomic_load(p, __ATOMIC_RELAXED, __HIP_MEMORY_SCOPE_AGENT) < tgt)
    __builtin_amdgcn_s_sleep(16);
}

#define FMA4(acc, xv, wv)                                                      \
  acc = fmaf((xv).x, (wv).x, acc); acc = fmaf((xv).y, (wv).y, acc);            \
  acc = fmaf((xv).z, (wv).z, acc); acc = fmaf((xv).w, (wv).w, acc)

// ---------------- enc GEMM: C[32768x512] = A[32768x1024] @ B[512x1024]^T + bias
__global__ __launch_bounds__(256) void kenc(const float* __restrict__ A,
                                            const float* __restrict__ Bm,
                                            const float* __restrict__ bias,
                                            float* __restrict__ C) {
  __shared__ float a_s[16][132];
  __shared__ float b_s[16][132];
  const int t = threadIdx.x;
  const int row = t >> 1;            // 0..127
  const int kq = (t & 1) * 8;        // 0 or 8
  const float* Arow = A + (blockIdx.x * 128 + row) * 1024 + kq;
  const float* Brow = Bm + (blockIdx.y * 128 + row) * 1024 + kq;
  const int tx = t & 15, ty = t >> 4;
  float acc[8][8] = {};
  for (int k0 = 0; k0 < 1024; k0 += 16) {
    float4 av0 = *(const float4*)(Arow + k0);
    float4 av1 = *(const float4*)(Arow + k0 + 4);
    float4 bv0 = *(const float4*)(Brow + k0);
    float4 bv1 = *(const float4*)(Brow + k0 + 4);
    __syncthreads();
    a_s[kq+0][row]=av0.x; a_s[kq+1][row]=av0.y; a_s[kq+2][row]=av0.z; a_s[kq+3][row]=av0.w;
    a_s[kq+4][row]=av1.x; a_s[kq+5][row]=av1.y; a_s[kq+6][row]=av1.z; a_s[kq+7][row]=av1.w;
    b_s[kq+0][row]=bv0.x; b_s[kq+1][row]=bv0.y; b_s[kq+2][row]=bv0.z; b_s[kq+3][row]=bv0.w;
    b_s[kq+4][row]=bv1.x; b_s[kq+5][row]=bv1.y; b_s[kq+6][row]=bv1.z; b_s[kq+7][row]=bv1.w;
    __syncthreads();
    #pragma unroll
    for (int k = 0; k < 16; ++k) {
      float a[8], b[8];
      *(float4*)(a)   = *(const float4*)&a_s[k][ty*4];
      *(float4*)(a+4) = *(const float4*)&a_s[k][64 + ty*4];
      *(float4*)(b)   = *(const float4*)&b_s[k][tx*4];
      *(float4*)(b+4) = *(const float4*)&b_s[k][64 + tx*4];
      #pragma unroll
      for (int i = 0; i < 8; ++i)
        #pragma unroll
        for (int j = 0; j < 8; ++j)
          acc[i][j] = fmaf(a[i], b[j], acc[i][j]);
    }
  }
  const int mb = blockIdx.x * 128;
  const int eb = blockIdx.y * 128;
  float4 bv0 = *(const float4*)&bias[eb + tx*4];
  float4 bv1 = *(const float4*)&bias[eb + 64 + tx*4];
  #pragma unroll
  for (int i = 0; i < 8; ++i) {
    const int r = mb + ((i < 4) ? (ty*4 + i) : (64 + ty*4 + (i - 4)));
    float* orow = C + r * 512 + eb;
    float4 o0, o1;
    o0.x=acc[i][0]+bv0.x; o0.y=acc[i][1]+bv0.y; o0.z=acc[i][2]+bv0.z; o0.w=acc[i][3]+bv0.w;
    o1.x=acc[i][4]+bv1.x; o1.y=acc[i][5]+bv1.y; o1.z=acc[i][6]+bv1.z; o1.w=acc[i][7]+bv1.w;
    *(float4*)(orow + tx*4) = o0;
    *(float4*)(orow + 64 + tx*4) = o1;
  }
}

// ---------------- fused per-step kernel. 1024 blocks x 256 threads.
// blocks 0..255:   gather + gates -> hx(atomic) |sig/wait| q(atomic) |sig|
// blocks 960..1023: logp + out_idx for step-1 (kernel-boundary inputs)
// all blocks:      wait q -> scores chunk (b=g>>4, 32 n) + atomicMax mall[step]
__global__ __launch_bounds__(256, 4) void kdec(
    const float* __restrict__ TE, const float* __restrict__ encd,
    const float* __restrict__ W_ih, const float* __restrict__ b_ih,
    const float* __restrict__ b_hh, const float* __restrict__ Wd,
    const float* __restrict__ bd, const float* __restrict__ wr,
    const float* __restrict__ br, const float* __restrict__ enc,
    float* __restrict__ scores,
    unsigned long long* __restrict__ hx_u, unsigned long long* __restrict__ q_u,
    unsigned long long* __restrict__ mall, unsigned* __restrict__ flags,
    float* __restrict__ out_logp, float* __restrict__ out_idx, int step) {
  __shared__ int   idx_s[64];
  __shared__ float wsum_s[4];
  __shared__ float part_s[4][64][6];
  __shared__ float partq_s[4][64][2];
  __shared__ unsigned long long lmax;
  const int g = blockIdx.x;
  const int t = threadIdx.x;
  const int lane = t & 63;
  const int wu = __builtin_amdgcn_readfirstlane(t >> 6);
  unsigned* hxd = flags + step * 64;        // separate cachelines
  unsigned* qd  = hxd + 32;

  if (g < 256) {
    // ---- gather indices for this step (mall[step-1] written by prev kernel)
    if (step > 0 && t < 64) idx_s[t] = unpack_idx(mall[(step - 1) * 64 + t]);
    __syncthreads();

    // ---- gates GEMM slice -> hx cols 2g, 2g+1 (i,g,o gates; f-gate dead)
    const int k0 = 2 * g, k1 = 2 * g + 1;
    {
      const int dbase = wu * 256;
      const float* p0 = W_ih + (k0        ) * 1024 + dbase;
      const float* p1 = W_ih + (k1        ) * 1024 + dbase;
      const float* p2 = W_ih + (1024 + k0) * 1024 + dbase;
      const float* p3 = W_ih + (1024 + k1) * 1024 + dbase;
      const float* p4 = W_ih + (1536 + k0) * 1024 + dbase;
      const float* p5 = W_ih + (1536 + k1) * 1024 + dbase;
      const float* xr = (step == 0) ? (encd + lane * 1024 + dbase)
                                    : (TE + (lane * 512 + idx_s[lane]) * 1024 + dbase);
      float a0=0, a1=0, a2=0, a3=0, a4=0, a5=0;
      #pragma unroll 4
      for (int d = 0; d < 256; d += 4) {
        float4 xv = *(const float4*)(xr + d);
        float4 v0 = *(const float4*)(p0 + d);
        float4 v1 = *(const float4*)(p1 + d);
        float4 v2 = *(const float4*)(p2 + d);
        float4 v3 = *(const float4*)(p3 + d);
        float4 v4 = *(const float4*)(p4 + d);
        float4 v5 = *(const float4*)(p5 + d);
        FMA4(a0, xv, v0); FMA4(a1, xv, v1); FMA4(a2, xv, v2);
        FMA4(a3, xv, v3); FMA4(a4, xv, v4); FMA4(a5, xv, v5);
      }
      part_s[wu][lane][0]=a0; part_s[wu][lane][1]=a1; part_s[wu][lane][2]=a2;
      part_s[wu][lane][3]=a3; part_s[wu][lane][4]=a4; part_s[wu][lane][5]=a5;
      __syncthreads();
      if (t < 64) {
        float s0=0, s1=0, s2=0, s3=0, s4=0, s5=0;
        #pragma unroll
        for (int u = 0; u < 4; ++u) {
          s0 += part_s[u][t][0]; s1 += part_s[u][t][1]; s2 += part_s[u][t][2];
          s3 += part_s[u][t][3]; s4 += part_s[u][t][4]; s5 += part_s[u][t][5];
        }
        const float gi0 = s0 + b_ih[k0] + b_hh[k0];
        const float gi1 = s1 + b_ih[k1] + b_hh[k1];
        const float gg0 = s2 + b_ih[1024 + k0] + b_hh[1024 + k0];
        const float gg1 = s3 + b_ih[1024 + k1] + b_hh[1024 + k1];
        const float go0 = s4 + b_ih[1536 + k0] + b_hh[1536 + k0];
        const float go1 = s5 + b_ih[1536 + k1] + b_hh[1536 + k1];
        const float c0 = sigm(gi0) * tanh_fast(gg0);
        const float c1 = sigm(gi1) * tanh_fast(gg1);
        // hx[t][k0], hx[t][k1] as one coherent u64 store
        st_f2(hx_u + t * 256 + g, sigm(go0) * tanh_fast(c0),
                                  sigm(go1) * tanh_fast(c1));
      }
    }
    __syncthreads();                       // drains hx stores (vmcnt0 @ barrier)
    if (t == 0) { sig(hxd); waitge(hxd, 256u); }
    __syncthreads();

    // ---- Q: q cols 2g, 2g+1 from coherent hx
    {
      const int dbase = wu * 128;
      const float* w0 = Wd + (k0) * 512 + dbase;
      const float* w1 = Wd + (k1) * 512 + dbase;
      const unsigned long long* xu = hx_u + lane * 256 + (dbase >> 1);
      float a0=0, a1=0;
      #pragma unroll 8
      for (int d = 0; d < 128; d += 4) {
        float2 xa = ld_f2(xu + (d >> 1));
        float2 xb = ld_f2(xu + (d >> 1) + 1);
        float4 xv; xv.x = xa.x; xv.y = xa.y; xv.z = xb.x; xv.w = xb.y;
        float4 v0 = *(const float4*)(w0 + d);
        float4 v1 = *(const float4*)(w1 + d);
        FMA4(a0, xv, v0); FMA4(a1, xv, v1);
      }
      partq_s[wu][lane][0]=a0; partq_s[wu][lane][1]=a1;
      __syncthreads();
      if (t < 64) {
        float rx = partq_s[0][t][0]+partq_s[1][t][0]+partq_s[2][t][0]+partq_s[3][t][0] + bd[k0];
        float ry = partq_s[0][t][1]+partq_s[1][t][1]+partq_s[2][t][1]+partq_s[3][t][1] + bd[k1];
        st_f2(q_u + t * 256 + g, rx, ry);
      }
    }
    __syncthreads();                       // drains q stores
    if (t == 0) sig(qd);
  } else if (g >= 960 && step > 0) {
    // ---- logp + out_idx for step-1 (inputs crossed the kernel boundary)
    const int b = g - 960;
    const unsigned long long p = mall[(step - 1) * 64 + b];
    const float mx = unpack_score(p);
    const float* srow = scores + b * 512;
    float ssum = __expf(srow[t] - mx) + __expf(srow[t + 256] - mx);
    #pragma unroll
    for (int m = 1; m <= 32; m <<= 1) ssum += __shfl_xor(ssum, m);
    if (lane == 0) wsum_s[wu] = ssum;
    __syncthreads();
    const float lse = mx + __logf(wsum_s[0] + wsum_s[1] + wsum_s[2] + wsum_s[3]);
    float* orow = out_logp + (b * 64 + (step - 1)) * 512;
    orow[t]       = srow[t]       - lse;
    orow[t + 256] = srow[t + 256] - lse;
    if (t == 0) out_idx[b * 64 + (step - 1)] = (float)unpack_idx(p);
  }

  // ---- S: all 1024 blocks wait for q, then scores chunk
  if (t == 0) { waitge(qd, 256u); lmax = 0ULL; }
  __syncthreads();
  {
    const int b = g >> 4, c = g & 15;
    const int le = lane & 15, nl = lane >> 4;
    const float C2 = 2.8853900817779268f;   // 2*log2(e)
    float4 wv[8], cq[8];
    const unsigned long long* qu = q_u + b * 256 + le * 2;
    const float* wrp = wr + le * 4;
    float swv = 0.0f;
    #pragma unroll
    for (int j = 0; j < 8; ++j) {
      wv[j] = *(const float4*)(wrp + 64 * j);
      swv += wv[j].x + wv[j].y + wv[j].z + wv[j].w;
      float2 qa = ld_f2(qu + 32 * j);
      float2 qb = ld_f2(qu + 32 * j + 1);
      cq[j].x = C2*qa.x; cq[j].y = C2*qa.y; cq[j].z = C2*qb.x; cq[j].w = C2*qb.y;
    }
    swv += __shfl_xor(swv, 1); swv += __shfl_xor(swv, 2);
    swv += __shfl_xor(swv, 4); swv += __shfl_xor(swv, 8);
    const float brv = br[0];
    #pragma unroll
    for (int i = 0; i < 2; ++i) {
      const int n = c * 32 + wu * 8 + i * 4 + nl;
      const float* erow = enc + (b * 512 + n) * 512 + le * 4;
      float acc = 0.0f;
      #pragma unroll
      for (int j = 0; j < 8; ++j) {
        float4 ev = *(const float4*)(erow + 64 * j);
        acc = fmaf(wv[j].x, __fdividef(1.0f, __builtin_exp2f(fmaf(C2, ev.x, cq[j].x)) + 1.0f), acc);
        acc = fmaf(wv[j].y, __fdividef(1.0f, __builtin_exp2f(fmaf(C2, ev.y, cq[j].y)) + 1.0f), acc);
        acc = fmaf(wv[j].z, __fdividef(1.0f, __builtin_exp2f(fmaf(C2, ev.z, cq[j].z)) + 1.0f), acc);
        acc = fmaf(wv[j].w, __fdividef(1.0f, __builtin_exp2f(fmaf(C2, ev.w, cq[j].w)) + 1.0f), acc);
      }
      acc += __shfl_xor(acc, 1); acc += __shfl_xor(acc, 2);
      acc += __shfl_xor(acc, 4); acc += __shfl_xor(acc, 8);
      if (le == 0) {
        const float sc = swv - 2.0f * acc + brv;
        scores[b * 512 + n] = sc;
        atomicMax(&lmax, pack_score(sc, n));
      }
    }
  }
  __syncthreads();
  if (t == 0) atomicMax(&mall[step * 64 + (g >> 4)], lmax);
}

// ---------------- final-step softmax/argmax (writes t=63 outputs)
__global__ __launch_bounds__(256) void kfin(const float* __restrict__ scores,
                                            const unsigned long long* __restrict__ mtop,
                                            float* __restrict__ out_logp,
                                            float* __restrict__ out_idx) {
  __shared__ float sw[4];
  const int b = blockIdx.x, t = threadIdx.x, lane = t & 63, w = t >> 6;
  const float* srow = scores + b * 512;
  const float s1 = srow[t], s2 = srow[t + 256];
  const unsigned long long p = mtop[b];
  const float mx = unpack_score(p);
  float ssum = __expf(s1 - mx) + __expf(s2 - mx);
  #pragma unroll
  for (int m = 1; m <= 32; m <<= 1) ssum += __shfl_xor(ssum, m);
  if (lane == 0) sw[w] = ssum;
  __syncthreads();
  const float lse = mx + __logf(sw[0] + sw[1] + sw[2] + sw[3]);
  float* orow = out_logp + (b * 64 + 63) * 512;
  orow[t]       = s1 - lse;
  orow[t + 256] = s2 - lse;
  if (t == 0) out_idx[b * 64 + 63] = (float)unpack_idx(p);
}

extern "C" void kernel_launch(void* const* d_in, const int* in_sizes, int n_in,
                              void* d_out, int out_size, void* d_ws, size_t ws_size,
                              hipStream_t stream) {
  const float* TE   = (const float*)d_in[0];   // [64,512,1024]
  const float* encd = (const float*)d_in[1];   // [64,1024]
  const float* W_ih = (const float*)d_in[2];   // [2048,1024]
  const float* b_ih = (const float*)d_in[3];   // [2048]
  const float* b_hh = (const float*)d_in[4];   // [2048]
  const float* Wd   = (const float*)d_in[5];   // [512,512]
  const float* bd   = (const float*)d_in[6];   // [512]
  const float* We   = (const float*)d_in[7];   // [512,1024]
  const float* be   = (const float*)d_in[8];   // [512]
  const float* wr   = (const float*)d_in[9];   // [512]
  const float* br   = (const float*)d_in[10];  // [1]

  float* out     = (float*)d_out;              // logp [64][64][512]
  float* out_idx = out + 64 * 64 * 512;        // indices as float [64][64]

  float* enc    = (float*)d_ws;                            // 16,777,216 f (64 MB)
  float* scores = enc + 16777216;                          // 32,768 f
  unsigned long long* hx_u = (unsigned long long*)(scores + 32768);  // 16384 u64
  unsigned long long* q_u  = hx_u + 16384;                           // 16384 u64
  unsigned long long* mall = q_u + 16384;                            // [64][64] u64
  unsigned* flags = (unsigned*)(mall + 64 * 64);                     // [64][64] u32

  hipMemsetAsync(mall, 0, 64 * 64 * 8 + 64 * 64 * 4, stream);
  kenc<<<dim3(256, 4), 256, 0, stream>>>(TE, We, be, enc);
  for (int t = 0; t < 64; ++t) {
    kdec<<<1024, 256, 0, stream>>>(TE, encd, W_ih, b_ih, b_hh, Wd, bd, wr, br,
                                   enc, scores, hx_u, q_u, mall, flags, out,
                                   out_idx, t);
  }
  kfin<<<64, 256, 0, stream>>>(scores, mall + 63 * 64, out, out_idx);
}